// Round 2
// baseline (409.342 us; speedup 1.0000x reference)
//
#include <hip/hip_runtime.h>
#include <hip/hip_fp16.h>
#include <cstdint>
#include <cstddef>

#define NB   4096   // batch
#define ND   128    // feature dim
#define OUTW 16384  // 4*NB output row width
#define CG   16     // col groups (blockIdx.x); each covers 8192/CG logical cols
#define IT   (8192 / CG / 64)   // 64-col tiles per block = 8

// 10 * log2(e): logits = cos/T = 10*acc; exp(10a-10) = 2^(K2*a - K2)
#define K2   14.4269504088896341f

typedef _Float16 f16;
typedef __attribute__((ext_vector_type(2))) _Float16 f16x2;
typedef __attribute__((ext_vector_type(8))) _Float16 f16x8;
typedef __attribute__((ext_vector_type(4))) float   f32x4;

// ---------------------------------------------------------------------------
// Kernel 1: l2-normalize z1,z2 rows, cast to f16; also zero rowsum (8192 f32).
// One wave per row.
// ---------------------------------------------------------------------------
__global__ __launch_bounds__(256) void nrm_kernel(const float* __restrict__ z1,
                                                  const float* __restrict__ z2,
                                                  f16* __restrict__ ab,
                                                  float* __restrict__ rowsum) {
  if (threadIdx.x < 4) rowsum[blockIdx.x * 4 + threadIdx.x] = 0.0f;
  int row  = blockIdx.x * 4 + (threadIdx.x >> 6);
  int lane = threadIdx.x & 63;
  const float* src = (row < NB) ? (z1 + (size_t)row * ND)
                                : (z2 + (size_t)(row - NB) * ND);
  float2 v = ((const float2*)src)[lane];
  float ss = v.x * v.x + v.y * v.y;
#pragma unroll
  for (int off = 32; off; off >>= 1) ss += __shfl_xor(ss, off);
  float r = rsqrtf(fmaxf(ss, 1e-12f));
  f16x2 h;
  h.x = (f16)(v.x * r);
  h.y = (f16)(v.y * r);
  ((f16x2*)(ab + (size_t)row * ND))[lane] = h;
}

// ---------------------------------------------------------------------------
// Fused GEMM pass: computes deferred-normalized numerators
//   p = exp2(K2*acc - K2)  (diag masked to 0),
// accumulates rowsums (atomic flush, as before), and stores p as f16 into a
// BLOCK-PRIVATE CONTIGUOUS 128 KB tile of ws:
//   tile[tid = rt*CG+g][row_l 0..127][512 cols (it*64+col_l)]  (row-major)
// so all stores of a block land in one 128 KB span -> L2 merges the 32B
// granules, lines evict fully-written & sequential (no DRAM row thrash).
// GEMM core identical to the verified pass_kernel.
// ---------------------------------------------------------------------------
__global__ __launch_bounds__(256, 2) void gemmp_kernel(const f16* __restrict__ ab,
                                                       float* __restrict__ rowsum,
                                                       f16* __restrict__ p16) {
  __shared__ f16 Bs[2][64 * ND];   // 2 x 16 KB

  const int t    = threadIdx.x;
  const int wave = t >> 6;
  const int lane = t & 63;
  const int wr   = wave >> 1;
  const int wc   = wave & 1;
  const int quad = lane >> 4;
  const int l16  = lane & 15;

  const int rt    = blockIdx.y;            // 0..63
  const int type  = rt >> 5;               // 0 = part1 (query a), 1 = part2 (b)
  const int r0    = (rt & 31) * 128;       // query row base in [0,4096)
  const int g     = blockIdx.x;            // 0..CG-1
  const int h2    = (g >= CG / 2) ? 1 : 0; // own-matrix half (diag masked)
  const int cbl   = g * (8192 / CG);       // logical col base (0..8191)
  const int cbase = cbl & (NB - 1);        // within-matrix col base
  const f16* Q  = ab + (size_t)type * NB * ND;
  const f16* Kp = ab + (size_t)(h2 ? type : (type ^ 1)) * NB * ND;

  // block-private tile base: 65536 f16 = 128 KB per block
  f16* tp = p16 + ((size_t)(rt * CG + g) << 16);

  // ---- A fragments: K=128 fully in registers (L2-hot global reads).
  f16x8 af[4][4];
  {
    const int arow = r0 + wr * 64 + l16;
#pragma unroll
    for (int mi = 0; mi < 4; ++mi)
#pragma unroll
      for (int ks = 0; ks < 4; ++ks)
        af[mi][ks] = *(const f16x8*)(Q + (size_t)(arow + mi * 16) * ND +
                                     ks * 32 + quad * 8);
  }

  const int sub = t >> 4;   // 0..15
  const int oct = t & 15;
  auto stage_b = [&](f16* buf, int kc0) {
#pragma unroll
    for (int i = 0; i < 4; ++i) {
      int rowl = i * 16 + sub;
      int goct = oct ^ (rowl & 15);
      __builtin_amdgcn_global_load_lds(
          (const __attribute__((address_space(1))) void*)(
              Kp + (size_t)(kc0 + rowl) * ND + goct * 8),
          (__attribute__((address_space(3))) void*)(buf + rowl * ND + oct * 8),
          16, 0, 0);
    }
  };

  float ps[4][4];
#pragma unroll
  for (int mi = 0; mi < 4; ++mi)
#pragma unroll
    for (int r = 0; r < 4; ++r) ps[mi][r] = 0.0f;

  stage_b(Bs[0], cbase);
  __syncthreads();

  for (int it = 0; it < IT; ++it) {
    if (it + 1 < IT) stage_b(Bs[(it + 1) & 1], cbase + (it + 1) * 64);

    const f16* buf = Bs[it & 1];
    f32x4 acc[4][2] = {};
#pragma unroll
    for (int ks = 0; ks < 4; ++ks) {
      int sw = (((ks * 4 + quad) ^ l16)) * 8;
      f16x8 bf0 = *(const f16x8*)(buf + (wc * 32 + l16) * ND + sw);
      f16x8 bf1 = *(const f16x8*)(buf + (wc * 32 + 16 + l16) * ND + sw);
#pragma unroll
      for (int mi = 0; mi < 4; ++mi) {
        acc[mi][0] = __builtin_amdgcn_mfma_f32_16x16x32_f16(af[mi][ks], bf0,
                                                            acc[mi][0], 0, 0, 0);
        acc[mi][1] = __builtin_amdgcn_mfma_f32_16x16x32_f16(af[mi][ks], bf1,
                                                            acc[mi][1], 0, 0, 0);
      }
    }

    const int c0m = cbase + it * 64;                 // within-matrix col base
    const bool dtile = h2 && (c0m == r0 || c0m == r0 + 64);

#pragma unroll
    for (int mi = 0; mi < 4; ++mi) {
#pragma unroll
      for (int ni = 0; ni < 2; ++ni) {
        int col_l = wc * 32 + ni * 16 + l16;
#pragma unroll
        for (int r = 0; r < 4; ++r) {
          int row_l = wr * 64 + mi * 16 + quad * 4 + r;
          float e = __builtin_amdgcn_exp2f(fmaf(acc[mi][ni][r], K2, -K2));
          if (dtile && (c0m + col_l == r0 + row_l)) e = 0.0f;
          ps[mi][r] += e;
          tp[row_l * 512 + it * 64 + col_l] = (f16)e;
        }
      }
    }
    __syncthreads();
  }

  // reduce each ps over the 16 cols (l16) and flush: 2 atomics/row/block.
#pragma unroll
  for (int mi = 0; mi < 4; ++mi)
#pragma unroll
    for (int r = 0; r < 4; ++r) {
      float v = ps[mi][r];
#pragma unroll
      for (int off = 1; off < 16; off <<= 1) v += __shfl_xor(v, off);
      if (l16 == 0) {
        int row_l = wr * 64 + mi * 16 + quad * 4 + r;
        atomicAdd(&rowsum[rt * 128 + row_l], v);
      }
    }
}

// ---------------------------------------------------------------------------
// Tile-major rescale: one block per 128x512 tile. Per wave-iteration:
// read one tile-row (1 KB f16, fully sequential/coalesced), scale by
// 1/rowsum (LDS-staged), write one 2 KB contiguous f32 segment of the final
// output row (NT stores -> no L3 pollution, p16 stays L3-resident).
// ---------------------------------------------------------------------------
__global__ __launch_bounds__(256) void rescale_kernel(const f16* __restrict__ p16,
                                                      const float* __restrict__ rowsum,
                                                      float* __restrict__ out) {
  __shared__ float cs[128];
  const int tid  = blockIdx.x;             // 0..1023 (= rt*CG + g)
  const int g    = tid & (CG - 1);
  const int rt   = tid >> 4;
  const int type = rt >> 5;
  const int r0   = (rt & 31) * 128;
  const int cb   = type * 8192 + g * (8192 / CG);   // final col base

  if (threadIdx.x < 128)
    cs[threadIdx.x] =
        __builtin_amdgcn_rcpf(rowsum[rt * 128 + threadIdx.x]);
  __syncthreads();

  const f16* tp = p16 + ((size_t)tid << 16);
  const int w = threadIdx.x >> 6;
  const int l = threadIdx.x & 63;

#pragma unroll 4
  for (int k = 0; k < 32; ++k) {
    int row_l = k * 4 + w;                 // each wave owns one tile-row
    f16x8 h = *(const f16x8*)(tp + row_l * 512 + l * 8);
    float inv = cs[row_l];
    f32x4 o0, o1;
    o0.x = (float)h[0] * inv; o0.y = (float)h[1] * inv;
    o0.z = (float)h[2] * inv; o0.w = (float)h[3] * inv;
    o1.x = (float)h[4] * inv; o1.y = (float)h[5] * inv;
    o1.z = (float)h[6] * inv; o1.w = (float)h[7] * inv;
    float* op = out + (size_t)(r0 + row_l) * OUTW + cb + l * 8;
    __builtin_nontemporal_store(o0, (f32x4*)op);
    __builtin_nontemporal_store(o1, (f32x4*)(op + 4));
  }
}

// ---------------------------------------------------------------------------
// Fallback path (previous verified kernel) when workspace is too small.
// ---------------------------------------------------------------------------
template <bool WRITE>
__global__ __launch_bounds__(256, 2) void pass_kernel(const f16* __restrict__ ab,
                                                      float* __restrict__ rowsum,
                                                      float* __restrict__ out) {
  __shared__ f16 Bs[2][64 * ND];   // 2 x 16 KB
  __shared__ float cs[128];

  const int t    = threadIdx.x;
  const int wave = t >> 6;
  const int lane = t & 63;
  const int wr   = wave >> 1;
  const int wc   = wave & 1;
  const int quad = lane >> 4;
  const int l16  = lane & 15;

  const int rt    = blockIdx.y;
  const int type  = rt >> 5;
  const int r0    = (rt & 31) * 128;
  const int g     = blockIdx.x;
  const int h2    = (g >= CG / 2) ? 1 : 0;
  const int cbl   = g * (8192 / CG);
  const int cbase = cbl & (NB - 1);
  const f16* Q  = ab + (size_t)type * NB * ND;
  const f16* Kp = ab + (size_t)(h2 ? type : (type ^ 1)) * NB * ND;

  f16x8 af[4][4];
  {
    const int arow = r0 + wr * 64 + l16;
#pragma unroll
    for (int mi = 0; mi < 4; ++mi)
#pragma unroll
      for (int ks = 0; ks < 4; ++ks)
        af[mi][ks] = *(const f16x8*)(Q + (size_t)(arow + mi * 16) * ND +
                                     ks * 32 + quad * 8);
  }

  const int sub = t >> 4;
  const int oct = t & 15;
  auto stage_b = [&](f16* buf, int kc0) {
#pragma unroll
    for (int i = 0; i < 4; ++i) {
      int rowl = i * 16 + sub;
      int goct = oct ^ (rowl & 15);
      __builtin_amdgcn_global_load_lds(
          (const __attribute__((address_space(1))) void*)(
              Kp + (size_t)(kc0 + rowl) * ND + goct * 8),
          (__attribute__((address_space(3))) void*)(buf + rowl * ND + oct * 8),
          16, 0, 0);
    }
  };

  float ps[4][4];
  if (!WRITE) {
#pragma unroll
    for (int mi = 0; mi < 4; ++mi)
#pragma unroll
      for (int r = 0; r < 4; ++r) ps[mi][r] = 0.0f;
  }

  stage_b(Bs[0], cbase);
  if (WRITE) {
    if (t < 128) cs[t] = -__log2f(rowsum[rt * 128 + t]) - K2;
  }
  __syncthreads();

  for (int it = 0; it < IT; ++it) {
    if (it + 1 < IT) stage_b(Bs[(it + 1) & 1], cbase + (it + 1) * 64);

    const f16* buf = Bs[it & 1];
    f32x4 acc[4][2] = {};
#pragma unroll
    for (int ks = 0; ks < 4; ++ks) {
      int sw = (((ks * 4 + quad) ^ l16)) * 8;
      f16x8 bf0 = *(const f16x8*)(buf + (wc * 32 + l16) * ND + sw);
      f16x8 bf1 = *(const f16x8*)(buf + (wc * 32 + 16 + l16) * ND + sw);
#pragma unroll
      for (int mi = 0; mi < 4; ++mi) {
        acc[mi][0] = __builtin_amdgcn_mfma_f32_16x16x32_f16(af[mi][ks], bf0,
                                                            acc[mi][0], 0, 0, 0);
        acc[mi][1] = __builtin_amdgcn_mfma_f32_16x16x32_f16(af[mi][ks], bf1,
                                                            acc[mi][1], 0, 0, 0);
      }
    }

    const int c0m = cbase + it * 64;
    const bool dtile = h2 && (c0m == r0 || c0m == r0 + 64);

    if (WRITE) {
      float4 cf[4];
#pragma unroll
      for (int mi = 0; mi < 4; ++mi)
        cf[mi] = *(const float4*)&cs[wr * 64 + mi * 16 + quad * 4];
#pragma unroll
      for (int mi = 0; mi < 4; ++mi) {
        const float* cp = &cf[mi].x;
#pragma unroll
        for (int ni = 0; ni < 2; ++ni) {
          int col_l = wc * 32 + ni * 16 + l16;
          size_t cout = (size_t)type * 8192 + cbl + it * 64 + col_l;
#pragma unroll
          for (int r = 0; r < 4; ++r) {
            int row_l = wr * 64 + mi * 16 + quad * 4 + r;
            float e = __builtin_amdgcn_exp2f(fmaf(acc[mi][ni][r], K2, cp[r]));
            if (dtile && (c0m + col_l == r0 + row_l)) e = 0.0f;
            out[(size_t)(r0 + row_l) * OUTW + cout] = e;
          }
        }
      }
    } else {
#pragma unroll
      for (int mi = 0; mi < 4; ++mi) {
#pragma unroll
        for (int ni = 0; ni < 2; ++ni) {
          int col_l = wc * 32 + ni * 16 + l16;
#pragma unroll
          for (int r = 0; r < 4; ++r) {
            int row_l = wr * 64 + mi * 16 + quad * 4 + r;
            float e = __builtin_amdgcn_exp2f(fmaf(acc[mi][ni][r], K2, -K2));
            if (dtile && (c0m + col_l == r0 + row_l)) e = 0.0f;
            ps[mi][r] += e;
          }
        }
      }
    }
    __syncthreads();
  }

  if (!WRITE) {
#pragma unroll
    for (int mi = 0; mi < 4; ++mi)
#pragma unroll
      for (int r = 0; r < 4; ++r) {
        float v = ps[mi][r];
#pragma unroll
        for (int off = 1; off < 16; off <<= 1) v += __shfl_xor(v, off);
        if (l16 == 0) {
          int row_l = wr * 64 + mi * 16 + quad * 4 + r;
          atomicAdd(&rowsum[rt * 128 + row_l], v);
        }
      }
  }
}

// ---------------------------------------------------------------------------
extern "C" void kernel_launch(void* const* d_in, const int* in_sizes, int n_in,
                              void* d_out, int out_size, void* d_ws, size_t ws_size,
                              hipStream_t stream) {
  const float* z1 = (const float*)d_in[0];
  const float* z2 = (const float*)d_in[1];
  float* out = (float*)d_out;

  const size_t ab_bytes = (size_t)8192 * ND * sizeof(f16);   // 2 MB
  const size_t rs_bytes = (size_t)8192 * sizeof(float);      // 32 KB
  const size_t p_bytes  = (size_t)NB * OUTW * sizeof(f16);   // 128 MiB

  f16* ab = (f16*)d_ws;
  float* rowsum = (float*)((char*)d_ws + ab_bytes);
  f16* p16 = (f16*)((char*)d_ws + ab_bytes + rs_bytes);

  nrm_kernel<<<2048, 256, 0, stream>>>(z1, z2, ab, rowsum);
  dim3 grid(CG, 64);
  if (ws_size >= ab_bytes + rs_bytes + p_bytes) {
    gemmp_kernel<<<grid, 256, 0, stream>>>(ab, rowsum, p16);
    rescale_kernel<<<1024, 256, 0, stream>>>(p16, rowsum, out);
  } else {
    pass_kernel<false><<<grid, 256, 0, stream>>>(ab, rowsum, out);
    pass_kernel<true><<<grid, 256, 0, stream>>>(ab, rowsum, out);
  }
}

// Round 3
// 380.325 us; speedup vs baseline: 1.0763x; 1.0763x over previous
//
#include <hip/hip_runtime.h>
#include <hip/hip_fp16.h>
#include <cstdint>
#include <cstddef>

#define NB   4096   // batch
#define ND   128    // feature dim
#define OUTW 16384  // 4*NB output row width
#define CG   16     // col groups (blockIdx.x); each covers 8192/CG logical cols
#define IT   (8192 / CG / 64)   // 64-col tiles per block = 8

// 10 * log2(e): logits = cos/T = 10*acc; exp(10a-10) = 2^(K2*a - K2)
#define K2   14.4269504088896341f

typedef _Float16 f16;
typedef __attribute__((ext_vector_type(2))) _Float16 f16x2;
typedef __attribute__((ext_vector_type(8))) _Float16 f16x8;
typedef __attribute__((ext_vector_type(4))) float   f32x4;

// ---------------------------------------------------------------------------
// Kernel 1: l2-normalize z1,z2 rows, cast to f16; also zero rowsum (8192 f32).
// One wave per row.
// ---------------------------------------------------------------------------
__global__ __launch_bounds__(256) void nrm_kernel(const float* __restrict__ z1,
                                                  const float* __restrict__ z2,
                                                  f16* __restrict__ ab,
                                                  float* __restrict__ rowsum) {
  if (threadIdx.x < 4) rowsum[blockIdx.x * 4 + threadIdx.x] = 0.0f;
  int row  = blockIdx.x * 4 + (threadIdx.x >> 6);
  int lane = threadIdx.x & 63;
  const float* src = (row < NB) ? (z1 + (size_t)row * ND)
                                : (z2 + (size_t)(row - NB) * ND);
  float2 v = ((const float2*)src)[lane];
  float ss = v.x * v.x + v.y * v.y;
#pragma unroll
  for (int off = 32; off; off >>= 1) ss += __shfl_xor(ss, off);
  float r = rsqrtf(fmaxf(ss, 1e-12f));
  f16x2 h;
  h.x = (f16)(v.x * r);
  h.y = (f16)(v.y * r);
  ((f16x2*)(ab + (size_t)row * ND))[lane] = h;
}

// ---------------------------------------------------------------------------
// Fused GEMM pass: computes deferred-normalized numerators
//   p = exp2(K2*acc - K2)  (diag masked to 0),
// accumulates rowsums (atomic flush), and stores p as f16 into a
// block-private 128 KB tile in PER-ITERATION-CONTIGUOUS layout:
//   tile[tid = rt*CG+g][it 0..7][row_l 0..127][64 cols]
// Each iteration's stores densely fill one 16 KB chunk -> live write-window
// is 16 KB/block (1 MB/XCD at 2-deep occupancy), lines fully written before
// eviction -> pure streaming write traffic. GEMM core = verified pass_kernel.
// ---------------------------------------------------------------------------
__global__ __launch_bounds__(256, 2) void gemmp_kernel(const f16* __restrict__ ab,
                                                       float* __restrict__ rowsum,
                                                       f16* __restrict__ p16) {
  __shared__ f16 Bs[2][64 * ND];   // 2 x 16 KB

  const int t    = threadIdx.x;
  const int wave = t >> 6;
  const int lane = t & 63;
  const int wr   = wave >> 1;
  const int wc   = wave & 1;
  const int quad = lane >> 4;
  const int l16  = lane & 15;

  const int rt    = blockIdx.y;            // 0..63
  const int type  = rt >> 5;               // 0 = part1 (query a), 1 = part2 (b)
  const int r0    = (rt & 31) * 128;       // query row base in [0,4096)
  const int g     = blockIdx.x;            // 0..CG-1
  const int h2    = (g >= CG / 2) ? 1 : 0; // own-matrix half (diag masked)
  const int cbl   = g * (8192 / CG);       // logical col base (0..8191)
  const int cbase = cbl & (NB - 1);        // within-matrix col base
  const f16* Q  = ab + (size_t)type * NB * ND;
  const f16* Kp = ab + (size_t)(h2 ? type : (type ^ 1)) * NB * ND;

  // block-private tile base: 65536 f16 = 128 KB per block
  f16* tp = p16 + ((size_t)(rt * CG + g) << 16);

  // ---- A fragments: K=128 fully in registers (L2-hot global reads).
  f16x8 af[4][4];
  {
    const int arow = r0 + wr * 64 + l16;
#pragma unroll
    for (int mi = 0; mi < 4; ++mi)
#pragma unroll
      for (int ks = 0; ks < 4; ++ks)
        af[mi][ks] = *(const f16x8*)(Q + (size_t)(arow + mi * 16) * ND +
                                     ks * 32 + quad * 8);
  }

  const int sub = t >> 4;   // 0..15
  const int oct = t & 15;
  auto stage_b = [&](f16* buf, int kc0) {
#pragma unroll
    for (int i = 0; i < 4; ++i) {
      int rowl = i * 16 + sub;
      int goct = oct ^ (rowl & 15);
      __builtin_amdgcn_global_load_lds(
          (const __attribute__((address_space(1))) void*)(
              Kp + (size_t)(kc0 + rowl) * ND + goct * 8),
          (__attribute__((address_space(3))) void*)(buf + rowl * ND + oct * 8),
          16, 0, 0);
    }
  };

  float ps[4][4];
#pragma unroll
  for (int mi = 0; mi < 4; ++mi)
#pragma unroll
    for (int r = 0; r < 4; ++r) ps[mi][r] = 0.0f;

  stage_b(Bs[0], cbase);
  __syncthreads();

  for (int it = 0; it < IT; ++it) {
    if (it + 1 < IT) stage_b(Bs[(it + 1) & 1], cbase + (it + 1) * 64);

    const f16* buf = Bs[it & 1];
    f32x4 acc[4][2] = {};
#pragma unroll
    for (int ks = 0; ks < 4; ++ks) {
      int sw = (((ks * 4 + quad) ^ l16)) * 8;
      f16x8 bf0 = *(const f16x8*)(buf + (wc * 32 + l16) * ND + sw);
      f16x8 bf1 = *(const f16x8*)(buf + (wc * 32 + 16 + l16) * ND + sw);
#pragma unroll
      for (int mi = 0; mi < 4; ++mi) {
        acc[mi][0] = __builtin_amdgcn_mfma_f32_16x16x32_f16(af[mi][ks], bf0,
                                                            acc[mi][0], 0, 0, 0);
        acc[mi][1] = __builtin_amdgcn_mfma_f32_16x16x32_f16(af[mi][ks], bf1,
                                                            acc[mi][1], 0, 0, 0);
      }
    }

    const int c0m = cbase + it * 64;                 // within-matrix col base
    const bool dtile = h2 && (c0m == r0 || c0m == r0 + 64);
    f16* tpi = tp + it * (128 * 64);                 // this iter's 16 KB chunk

#pragma unroll
    for (int mi = 0; mi < 4; ++mi) {
#pragma unroll
      for (int ni = 0; ni < 2; ++ni) {
        int col_l = wc * 32 + ni * 16 + l16;
#pragma unroll
        for (int r = 0; r < 4; ++r) {
          int row_l = wr * 64 + mi * 16 + quad * 4 + r;
          float e = __builtin_amdgcn_exp2f(fmaf(acc[mi][ni][r], K2, -K2));
          if (dtile && (c0m + col_l == r0 + row_l)) e = 0.0f;
          ps[mi][r] += e;
          tpi[row_l * 64 + col_l] = (f16)e;
        }
      }
    }
    __syncthreads();
  }

  // reduce each ps over the 16 cols (l16) and flush: 2 atomics/row/block.
#pragma unroll
  for (int mi = 0; mi < 4; ++mi)
#pragma unroll
    for (int r = 0; r < 4; ++r) {
      float v = ps[mi][r];
#pragma unroll
      for (int off = 1; off < 16; off <<= 1) v += __shfl_xor(v, off);
      if (l16 == 0) {
        int row_l = wr * 64 + mi * 16 + quad * 4 + r;
        atomicAdd(&rowsum[rt * 128 + row_l], v);
      }
    }
}

// ---------------------------------------------------------------------------
// Row-sequential rescale: one block per OUTPUT row (4096 blocks).
// Writes the full 64 KB output row sequentially (NT f32x4 pairs); gathers
// p16 in 128 B segments at 16 KB stride (read side strided = L2/L3-absorbed).
// Chunk c (0..31): type=c>>4, g=c&15 -> 512 cols at out[orow][c*512..].
// p16 addr: tile=((type*32+(orow>>7))*16+g), elem = (l>>3)*8192
//           + (orow&127)*64 + (l&7)*8  (f16x8 per lane).
// ---------------------------------------------------------------------------
__global__ __launch_bounds__(256) void rescale_kernel(const f16* __restrict__ p16,
                                                      const float* __restrict__ rowsum,
                                                      float* __restrict__ out) {
  const int orow = blockIdx.x;             // 0..4095
  const int w = threadIdx.x >> 6;
  const int l = threadIdx.x & 63;

  const float inv0 = __builtin_amdgcn_rcpf(rowsum[orow]);
  const float inv1 = __builtin_amdgcn_rcpf(rowsum[NB + orow]);

  const int strip = orow >> 7;             // 0..31
  const int rl64  = (orow & 127) * 64;
  const int loff  = (l >> 3) * 8192 + (l & 7) * 8;
  float* orow_p = out + (size_t)orow * OUTW;

#pragma unroll
  for (int k = 0; k < 8; ++k) {
    int c    = k * 4 + w;                  // 0..31
    int type = c >> 4;
    int gg   = c & 15;
    const f16* tp = p16 + ((size_t)(((type * 32 + strip) << 4) + gg) << 16);
    f16x8 h = *(const f16x8*)(tp + rl64 + loff);
    float inv = type ? inv1 : inv0;
    f32x4 o0, o1;
    o0.x = (float)h[0] * inv; o0.y = (float)h[1] * inv;
    o0.z = (float)h[2] * inv; o0.w = (float)h[3] * inv;
    o1.x = (float)h[4] * inv; o1.y = (float)h[5] * inv;
    o1.z = (float)h[6] * inv; o1.w = (float)h[7] * inv;
    float* op = orow_p + c * 512 + l * 8;
    __builtin_nontemporal_store(o0, (f32x4*)op);
    __builtin_nontemporal_store(o1, (f32x4*)(op + 4));
  }
}

// ---------------------------------------------------------------------------
// Fallback path (previous verified kernel) when workspace is too small.
// ---------------------------------------------------------------------------
template <bool WRITE>
__global__ __launch_bounds__(256, 2) void pass_kernel(const f16* __restrict__ ab,
                                                      float* __restrict__ rowsum,
                                                      float* __restrict__ out) {
  __shared__ f16 Bs[2][64 * ND];   // 2 x 16 KB
  __shared__ float cs[128];

  const int t    = threadIdx.x;
  const int wave = t >> 6;
  const int lane = t & 63;
  const int wr   = wave >> 1;
  const int wc   = wave & 1;
  const int quad = lane >> 4;
  const int l16  = lane & 15;

  const int rt    = blockIdx.y;
  const int type  = rt >> 5;
  const int r0    = (rt & 31) * 128;
  const int g     = blockIdx.x;
  const int h2    = (g >= CG / 2) ? 1 : 0;
  const int cbl   = g * (8192 / CG);
  const int cbase = cbl & (NB - 1);
  const f16* Q  = ab + (size_t)type * NB * ND;
  const f16* Kp = ab + (size_t)(h2 ? type : (type ^ 1)) * NB * ND;

  f16x8 af[4][4];
  {
    const int arow = r0 + wr * 64 + l16;
#pragma unroll
    for (int mi = 0; mi < 4; ++mi)
#pragma unroll
      for (int ks = 0; ks < 4; ++ks)
        af[mi][ks] = *(const f16x8*)(Q + (size_t)(arow + mi * 16) * ND +
                                     ks * 32 + quad * 8);
  }

  const int sub = t >> 4;
  const int oct = t & 15;
  auto stage_b = [&](f16* buf, int kc0) {
#pragma unroll
    for (int i = 0; i < 4; ++i) {
      int rowl = i * 16 + sub;
      int goct = oct ^ (rowl & 15);
      __builtin_amdgcn_global_load_lds(
          (const __attribute__((address_space(1))) void*)(
              Kp + (size_t)(kc0 + rowl) * ND + goct * 8),
          (__attribute__((address_space(3))) void*)(buf + rowl * ND + oct * 8),
          16, 0, 0);
    }
  };

  float ps[4][4];
  if (!WRITE) {
#pragma unroll
    for (int mi = 0; mi < 4; ++mi)
#pragma unroll
      for (int r = 0; r < 4; ++r) ps[mi][r] = 0.0f;
  }

  stage_b(Bs[0], cbase);
  if (WRITE) {
    if (t < 128) cs[t] = -__log2f(rowsum[rt * 128 + t]) - K2;
  }
  __syncthreads();

  for (int it = 0; it < IT; ++it) {
    if (it + 1 < IT) stage_b(Bs[(it + 1) & 1], cbase + (it + 1) * 64);

    const f16* buf = Bs[it & 1];
    f32x4 acc[4][2] = {};
#pragma unroll
    for (int ks = 0; ks < 4; ++ks) {
      int sw = (((ks * 4 + quad) ^ l16)) * 8;
      f16x8 bf0 = *(const f16x8*)(buf + (wc * 32 + l16) * ND + sw);
      f16x8 bf1 = *(const f16x8*)(buf + (wc * 32 + 16 + l16) * ND + sw);
#pragma unroll
      for (int mi = 0; mi < 4; ++mi) {
        acc[mi][0] = __builtin_amdgcn_mfma_f32_16x16x32_f16(af[mi][ks], bf0,
                                                            acc[mi][0], 0, 0, 0);
        acc[mi][1] = __builtin_amdgcn_mfma_f32_16x16x32_f16(af[mi][ks], bf1,
                                                            acc[mi][1], 0, 0, 0);
      }
    }

    const int c0m = cbase + it * 64;
    const bool dtile = h2 && (c0m == r0 || c0m == r0 + 64);

    if (WRITE) {
      float4 cf[4];
#pragma unroll
      for (int mi = 0; mi < 4; ++mi)
        cf[mi] = *(const float4*)&cs[wr * 64 + mi * 16 + quad * 4];
#pragma unroll
      for (int mi = 0; mi < 4; ++mi) {
        const float* cp = &cf[mi].x;
#pragma unroll
        for (int ni = 0; ni < 2; ++ni) {
          int col_l = wc * 32 + ni * 16 + l16;
          size_t cout = (size_t)type * 8192 + cbl + it * 64 + col_l;
#pragma unroll
          for (int r = 0; r < 4; ++r) {
            int row_l = wr * 64 + mi * 16 + quad * 4 + r;
            float e = __builtin_amdgcn_exp2f(fmaf(acc[mi][ni][r], K2, cp[r]));
            if (dtile && (c0m + col_l == r0 + row_l)) e = 0.0f;
            out[(size_t)(r0 + row_l) * OUTW + cout] = e;
          }
        }
      }
    } else {
#pragma unroll
      for (int mi = 0; mi < 4; ++mi) {
#pragma unroll
        for (int ni = 0; ni < 2; ++ni) {
          int col_l = wc * 32 + ni * 16 + l16;
#pragma unroll
          for (int r = 0; r < 4; ++r) {
            int row_l = wr * 64 + mi * 16 + quad * 4 + r;
            float e = __builtin_amdgcn_exp2f(fmaf(acc[mi][ni][r], K2, -K2));
            if (dtile && (c0m + col_l == r0 + row_l)) e = 0.0f;
            ps[mi][r] += e;
          }
        }
      }
    }
    __syncthreads();
  }

  if (!WRITE) {
#pragma unroll
    for (int mi = 0; mi < 4; ++mi)
#pragma unroll
      for (int r = 0; r < 4; ++r) {
        float v = ps[mi][r];
#pragma unroll
        for (int off = 1; off < 16; off <<= 1) v += __shfl_xor(v, off);
        if (l16 == 0) {
          int row_l = wr * 64 + mi * 16 + quad * 4 + r;
          atomicAdd(&rowsum[rt * 128 + row_l], v);
        }
      }
  }
}

// ---------------------------------------------------------------------------
extern "C" void kernel_launch(void* const* d_in, const int* in_sizes, int n_in,
                              void* d_out, int out_size, void* d_ws, size_t ws_size,
                              hipStream_t stream) {
  const float* z1 = (const float*)d_in[0];
  const float* z2 = (const float*)d_in[1];
  float* out = (float*)d_out;

  const size_t ab_bytes = (size_t)8192 * ND * sizeof(f16);   // 2 MB
  const size_t rs_bytes = (size_t)8192 * sizeof(float);      // 32 KB
  const size_t p_bytes  = (size_t)NB * OUTW * sizeof(f16);   // 128 MiB

  f16* ab = (f16*)d_ws;
  float* rowsum = (float*)((char*)d_ws + ab_bytes);
  f16* p16 = (f16*)((char*)d_ws + ab_bytes + rs_bytes);

  nrm_kernel<<<2048, 256, 0, stream>>>(z1, z2, ab, rowsum);
  dim3 grid(CG, 64);
  if (ws_size >= ab_bytes + rs_bytes + p_bytes) {
    gemmp_kernel<<<grid, 256, 0, stream>>>(ab, rowsum, p16);
    rescale_kernel<<<4096, 256, 0, stream>>>(p16, rowsum, out);
  } else {
    pass_kernel<false><<<grid, 256, 0, stream>>>(ab, rowsum, out);
    pass_kernel<true><<<grid, 256, 0, stream>>>(ab, rowsum, out);
  }
}

// Round 5
// 300.561 us; speedup vs baseline: 1.3619x; 1.2654x over previous
//
#include <hip/hip_runtime.h>
#include <hip/hip_fp16.h>
#include <cstdint>
#include <cstddef>

#define NB   4096   // batch
#define ND   128    // feature dim
#define OUTW 16384  // 4*NB output row width
#define CG   16     // col groups (blockIdx.x); each covers 8192/CG logical cols
#define IT   (8192 / CG / 64)   // 64-col tiles per block = 8

// 10 * log2(e): logits = cos/T = 10*acc; exp(10a-10) = 2^(K2*a - K2)
#define K2   14.4269504088896341f

typedef _Float16 f16;
typedef __attribute__((ext_vector_type(2))) _Float16 f16x2;
typedef __attribute__((ext_vector_type(8))) _Float16 f16x8;
typedef __attribute__((ext_vector_type(4))) float   f32x4;

// ---------------------------------------------------------------------------
// Kernel 1: l2-normalize z1,z2 rows, cast to f16; also zero rowsum (8192 f32).
// One wave per row.
// ---------------------------------------------------------------------------
__global__ __launch_bounds__(256) void nrm_kernel(const float* __restrict__ z1,
                                                  const float* __restrict__ z2,
                                                  f16* __restrict__ ab,
                                                  float* __restrict__ rowsum) {
  if (threadIdx.x < 4) rowsum[blockIdx.x * 4 + threadIdx.x] = 0.0f;
  int row  = blockIdx.x * 4 + (threadIdx.x >> 6);
  int lane = threadIdx.x & 63;
  const float* src = (row < NB) ? (z1 + (size_t)row * ND)
                                : (z2 + (size_t)(row - NB) * ND);
  float2 v = ((const float2*)src)[lane];
  float ss = v.x * v.x + v.y * v.y;
#pragma unroll
  for (int off = 32; off; off >>= 1) ss += __shfl_xor(ss, off);
  float r = rsqrtf(fmaxf(ss, 1e-12f));
  f16x2 h;
  h.x = (f16)(v.x * r);
  h.y = (f16)(v.y * r);
  ((f16x2*)(ab + (size_t)row * ND))[lane] = h;
}

// ---------------------------------------------------------------------------
// Two-pass streaming GEMM+softmax (verified 305 us structure), with ONE
// change: SWAPPED-OPERAND MFMA.  mfma(bf, af, acc) transposes the C/D lane
// mapping (col=lane&15 -> our output ROW; row=quad*4+reg -> our output COL),
// so each lane holds 4 CONSECUTIVE output columns of one row.  Epilogue:
//   WRITE=true : 8 global_store_dwordx4 / thread / iter (was 32 scalar dword)
//   WRITE=false: ps[mi] scalar per thread, 2-shuffle quad reduction.
// Everything else (staging, XOR-octet LDS swizzle, ds_reads, barriers)
// is byte-identical to the verified kernel.
// ---------------------------------------------------------------------------
template <bool WRITE>
__global__ __launch_bounds__(256, 2) void pass_kernel(const f16* __restrict__ ab,
                                                      float* __restrict__ rowsum,
                                                      float* __restrict__ out) {
  __shared__ f16 Bs[2][64 * ND];   // 2 x 16 KB
  __shared__ float cs[128];

  const int t    = threadIdx.x;
  const int wave = t >> 6;
  const int lane = t & 63;
  const int wr   = wave >> 1;
  const int wc   = wave & 1;
  const int quad = lane >> 4;
  const int l16  = lane & 15;

  const int rt    = blockIdx.y;            // 0..63
  const int type  = rt >> 5;               // 0 = part1 (query a), 1 = part2 (b)
  const int r0    = (rt & 31) * 128;       // query row base in [0,4096)
  const int g     = blockIdx.x;            // 0..CG-1
  const int h2    = (g >= CG / 2) ? 1 : 0; // own-matrix half (diag masked)
  const int cbl   = g * (8192 / CG);       // logical col base (0..8191)
  const int cbase = cbl & (NB - 1);        // within-matrix col base
  const f16* Q  = ab + (size_t)type * NB * ND;
  const f16* Kp = ab + (size_t)(h2 ? type : (type ^ 1)) * NB * ND;

  // ---- A fragments: K=128 fully in registers (L2-hot global reads).
  // 16x16x32 operand layout: lane(l16,quad) holds row l16, k = ks*32+quad*8..+7.
  f16x8 af[4][4];
  {
    const int arow = r0 + wr * 64 + l16;
#pragma unroll
    for (int mi = 0; mi < 4; ++mi)
#pragma unroll
      for (int ks = 0; ks < 4; ++ks)
        af[mi][ks] = *(const f16x8*)(Q + (size_t)(arow + mi * 16) * ND +
                                     ks * 32 + quad * 8);
  }

  const int sub = t >> 4;   // 0..15
  const int oct = t & 15;
  auto stage_b = [&](f16* buf, int kc0) {
#pragma unroll
    for (int i = 0; i < 4; ++i) {
      int rowl = i * 16 + sub;
      int goct = oct ^ (rowl & 15);
      __builtin_amdgcn_global_load_lds(
          (const __attribute__((address_space(1))) void*)(
              Kp + (size_t)(kc0 + rowl) * ND + goct * 8),
          (__attribute__((address_space(3))) void*)(buf + rowl * ND + oct * 8),
          16, 0, 0);
    }
  };

  float ps[4];
  if (!WRITE) {
#pragma unroll
    for (int mi = 0; mi < 4; ++mi) ps[mi] = 0.0f;
  }

  stage_b(Bs[0], cbase);
  if (WRITE) {
    if (t < 128) cs[t] = -__log2f(rowsum[rt * 128 + t]) - K2;
  }
  __syncthreads();

  for (int it = 0; it < IT; ++it) {
    if (it + 1 < IT) stage_b(Bs[(it + 1) & 1], cbase + (it + 1) * 64);

    const f16* buf = Bs[it & 1];
    f32x4 acc[4][2] = {};
#pragma unroll
    for (int ks = 0; ks < 4; ++ks) {
      int sw = (((ks * 4 + quad) ^ l16)) * 8;
      f16x8 bf0 = *(const f16x8*)(buf + (wc * 32 + l16) * ND + sw);
      f16x8 bf1 = *(const f16x8*)(buf + (wc * 32 + 16 + l16) * ND + sw);
#pragma unroll
      for (int mi = 0; mi < 4; ++mi) {
        // SWAPPED operands: D[i=bf-row][j=af-row]; lane holds j=l16 (out row),
        // i=quad*4+reg (out col) -> 4 consecutive cols per lane.
        acc[mi][0] = __builtin_amdgcn_mfma_f32_16x16x32_f16(bf0, af[mi][ks],
                                                            acc[mi][0], 0, 0, 0);
        acc[mi][1] = __builtin_amdgcn_mfma_f32_16x16x32_f16(bf1, af[mi][ks],
                                                            acc[mi][1], 0, 0, 0);
      }
    }

    const int c0m = cbase + it * 64;                 // within-matrix col base
    const bool dtile = h2 && (c0m == r0 || c0m == r0 + 64);

    if (WRITE) {
#pragma unroll
      for (int mi = 0; mi < 4; ++mi) {
        const int row_l = wr * 64 + mi * 16 + l16;
        const float c = cs[row_l];
        float* orow = out + (size_t)(r0 + row_l) * OUTW + (size_t)type * 8192 +
                      cbl + it * 64;
#pragma unroll
        for (int ni = 0; ni < 2; ++ni) {
          const int cq = wc * 32 + ni * 16 + quad * 4;   // col_l of reg 0
          f32x4 o;
#pragma unroll
          for (int r = 0; r < 4; ++r) {
            float e = __builtin_amdgcn_exp2f(fmaf(acc[mi][ni][r], K2, c));
            if (dtile && (c0m + cq + r == r0 + row_l)) e = 0.0f;
            o[r] = e;
          }
          *(f32x4*)(orow + cq) = o;
        }
      }
    } else {
#pragma unroll
      for (int mi = 0; mi < 4; ++mi) {
        const int row_l = wr * 64 + mi * 16 + l16;
#pragma unroll
        for (int ni = 0; ni < 2; ++ni) {
          const int cq = wc * 32 + ni * 16 + quad * 4;
#pragma unroll
          for (int r = 0; r < 4; ++r) {
            float e = __builtin_amdgcn_exp2f(fmaf(acc[mi][ni][r], K2, -K2));
            if (dtile && (c0m + cq + r == r0 + row_l)) e = 0.0f;
            ps[mi] += e;
          }
        }
      }
    }
    __syncthreads();
  }

  if (!WRITE) {
    // ps[mi] = this thread's partial for row (wr*64+mi*16+l16) over its 8 cols.
    // Sum over the 4 quads (lane bits 4,5), flush one atomic per row per wave.
#pragma unroll
    for (int mi = 0; mi < 4; ++mi) {
      float v = ps[mi];
      v += __shfl_xor(v, 16);
      v += __shfl_xor(v, 32);
      if (quad == 0) {
        int row_l = wr * 64 + mi * 16 + l16;
        atomicAdd(&rowsum[rt * 128 + row_l], v);
      }
    }
  }
}

// ---------------------------------------------------------------------------
extern "C" void kernel_launch(void* const* d_in, const int* in_sizes, int n_in,
                              void* d_out, int out_size, void* d_ws, size_t ws_size,
                              hipStream_t stream) {
  const float* z1 = (const float*)d_in[0];
  const float* z2 = (const float*)d_in[1];
  float* out = (float*)d_out;

  f16* ab = (f16*)d_ws;                                   // 8192x128 f16 = 2 MB
  float* rowsum = (float*)((char*)d_ws + (size_t)8192 * ND * sizeof(f16)); // 32 KB

  nrm_kernel<<<2048, 256, 0, stream>>>(z1, z2, ab, rowsum);
  dim3 grid(CG, 64);
  pass_kernel<false><<<grid, 256, 0, stream>>>(ab, rowsum, out);
  pass_kernel<true><<<grid, 256, 0, stream>>>(ab, rowsum, out);
}